// Round 1
// baseline (2865.544 us; speedup 1.0000x reference)
//
#include <hip/hip_runtime.h>
#include <stdint.h>

typedef int v4i __attribute__((ext_vector_type(4)));
typedef unsigned long long ull;

__device__ __forceinline__ signed char sgnf(float v) {
  return v > 0.f ? (signed char)1 : (v < 0.f ? (signed char)-1 : (signed char)0);
}

// ---------------- binarize fp32 -> i8 sign ----------------
__global__ void k_bin(const float4* __restrict__ in, char4* __restrict__ out, int n4) {
  int i = blockIdx.x * blockDim.x + threadIdx.x;
  int stride = gridDim.x * blockDim.x;
  for (; i < n4; i += stride) {
    float4 v = in[i];
    char4 o;
    o.x = sgnf(v.x); o.y = sgnf(v.y); o.z = sgnf(v.z); o.w = sgnf(v.w);
    out[i] = o;
  }
}

// ---------------- i8 binary GEMM: A[M,N] = X[M,K] * W[N,K]^T (dot only, int16 out) ----
#define BM 128
#define BN 128
#define BKB 128

__global__ __launch_bounds__(256) void k_bgemm(
    const signed char* __restrict__ X, const signed char* __restrict__ W,
    short* __restrict__ A, int M, int N, int K)
{
  __shared__ __align__(16) signed char As[BM * BKB];
  __shared__ __align__(16) signed char Bs[BN * BKB];
  const int t = threadIdx.x;
  const int lane = t & 63;
  const int wave = t >> 6;
  const int wm = wave >> 1, wn = wave & 1;
  const int bm = blockIdx.y * BM, bn = blockIdx.x * BN;
  const int r8 = t >> 3, s8 = t & 7;

  v4i acc[4][4] = {};

  for (int k0 = 0; k0 < K; k0 += BKB) {
    int4 ra[4], rb[4];
#pragma unroll
    for (int p = 0; p < 4; ++p) {
      int row = p * 32 + r8;
      ra[p] = *(const int4*)(X + (size_t)(bm + row) * K + k0 + s8 * 16);
      rb[p] = *(const int4*)(W + (size_t)(bn + row) * K + k0 + s8 * 16);
    }
    __syncthreads();   // previous tile's compute done before overwrite
#pragma unroll
    for (int p = 0; p < 4; ++p) {
      int row = p * 32 + r8;
      int ds = (s8 ^ (row & 7)) * 16;   // XOR swizzle: conflict-free ds_read_b128
      *(int4*)(As + row * BKB + ds) = ra[p];
      *(int4*)(Bs + row * BKB + ds) = rb[p];
    }
    __syncthreads();
#pragma unroll
    for (int kk = 0; kk < 2; ++kk) {
      v4i af[4], bf[4];
#pragma unroll
      for (int m = 0; m < 4; ++m) {
        int row = wm * 64 + m * 16 + (lane & 15);
        int slot = ((kk << 2) | (lane >> 4)) ^ (row & 7);
        af[m] = *(const v4i*)(As + row * BKB + slot * 16);
      }
#pragma unroll
      for (int n = 0; n < 4; ++n) {
        int row = wn * 64 + n * 16 + (lane & 15);
        int slot = ((kk << 2) | (lane >> 4)) ^ (row & 7);
        bf[n] = *(const v4i*)(Bs + row * BKB + slot * 16);
      }
#pragma unroll
      for (int m = 0; m < 4; ++m)
#pragma unroll
        for (int n = 0; n < 4; ++n)
          acc[m][n] = __builtin_amdgcn_mfma_i32_16x16x64_i8(af[m], bf[n], acc[m][n], 0, 0, 0);
    }
  }

  // C layout (verified, dtype-independent): col = lane&15, row = (lane>>4)*4 + reg
#pragma unroll
  for (int m = 0; m < 4; ++m) {
    int rbase = bm + wm * 64 + m * 16 + (lane >> 4) * 4;
#pragma unroll
    for (int n = 0; n < 4; ++n) {
      int col = bn + wn * 64 + n * 16 + (lane & 15);
#pragma unroll
      for (int r = 0; r < 4; ++r)
        A[(size_t)(rbase + r) * N + col] = (short)acc[m][n][r];
    }
  }
}

// ---------------- per-column int64 stats (sum, sumsq) via deterministic atomics ----
__global__ void k_colstats(const short* __restrict__ A, int M, int N, int rowsPerBlock,
                           ull* __restrict__ sums) {
  __shared__ long long ls[256], lsq[256];
  int t = threadIdx.x;
  int col = blockIdx.x * 64 + (t & 63);
  int rg = t >> 6;
  int r0 = blockIdx.y * rowsPerBlock;
  long long s = 0, sq = 0;
  for (int r = r0 + rg; r < r0 + rowsPerBlock; r += 4) {
    int v = A[(size_t)r * N + col];
    s += v; sq += (long long)(v * v);
  }
  ls[t] = s; lsq[t] = sq;
  __syncthreads();
  if (rg == 0) {
    s = ls[t] + ls[t + 64] + ls[t + 128] + ls[t + 192];
    sq = lsq[t] + lsq[t + 64] + lsq[t + 128] + lsq[t + 192];
    atomicAdd(&sums[col], (ull)s);
    atomicAdd(&sums[(size_t)N + col], (ull)sq);
  }
}

// ---------------- stats -> (mean, g*rsqrt(var+eps)) per column ----------------
__global__ void k_finalize(const ull* __restrict__ sums, const float* __restrict__ g,
                           int M, int N, float* __restrict__ meanf, float* __restrict__ sgf) {
  int j = blockIdx.x * blockDim.x + threadIdx.x;
  if (j >= N) return;
  double sum = (double)(long long)sums[j];
  double sumsq = (double)(long long)sums[N + j];
  double mean = sum / (double)M;
  double var = sumsq / (double)M - mean * mean;
  if (var < 0.0) var = 0.0;
  double inv = 1.0 / sqrt(var + 1e-5);
  meanf[j] = (float)mean;
  sgf[j] = (float)(inv * (double)g[j]);
}

// ---------------- sign(batchnorm(a)) -> i8 (bias cancels under BN) ----------------
__global__ void k_signbn(const short4* __restrict__ A4, const float* __restrict__ meanf,
                         const float* __restrict__ sgf, const float* __restrict__ be,
                         char4* __restrict__ X4, int total4, int nmask) {
  int i = blockIdx.x * blockDim.x + threadIdx.x;
  int stride = gridDim.x * blockDim.x;
  for (; i < total4; i += stride) {
    short4 a = A4[i];
    int c0 = (i * 4) & nmask;
    char4 o;
    o.x = sgnf(((float)a.x - meanf[c0    ]) * sgf[c0    ] + be[c0    ]);
    o.y = sgnf(((float)a.y - meanf[c0 + 1]) * sgf[c0 + 1] + be[c0 + 1]);
    o.z = sgnf(((float)a.z - meanf[c0 + 2]) * sgf[c0 + 2] + be[c0 + 2]);
    o.w = sgnf(((float)a.w - meanf[c0 + 3]) * sgf[c0 + 3] + be[c0 + 3]);
    X4[i] = o;
  }
}

// ---------------- fused layers 3,4,5: X3[M,256] -> A5[M,10] + stats ----------------
__global__ __launch_bounds__(256) void k_tail(
    const signed char* __restrict__ X3, const signed char* __restrict__ W3,
    const signed char* __restrict__ W4, const signed char* __restrict__ W5,
    const float* __restrict__ b3, const float* __restrict__ b4,
    int* __restrict__ A5, ull* __restrict__ sums5, int M)
{
  __shared__ __align__(16) signed char sW3[16 * 256];
  __shared__ __align__(16) signed char sW4[256];
  __shared__ __align__(16) signed char sW5[160];
  __shared__ __align__(16) signed char sX[16 * 256];
  __shared__ signed char sH[16][16];
  __shared__ int bsum[10], bsq[10];
  int t = threadIdx.x;
  int rowBlock = blockIdx.x * 16;
  ((int4*)sW3)[t] = ((const int4*)W3)[t];
  ((int4*)sX)[t] = ((const int4*)(X3 + (size_t)rowBlock * 256))[t];
  if (t < 16) ((int4*)sW4)[t] = ((const int4*)W4)[t];
  if (t < 10) {
    ((int4*)sW5)[t] = ((const int4*)W5)[t];
    bsum[t] = 0; bsq[t] = 0;
  }
  __syncthreads();
  int r = t >> 4, j = t & 15;
  int d3 = 0;
#pragma unroll 8
  for (int k = 0; k < 256; ++k) d3 += (int)sX[r * 256 + k] * (int)sW3[j * 256 + k];
  sH[r][j] = sgnf((float)d3 + b3[j]);   // sign(hardtanh(z)) == sign(z)
  __syncthreads();
  int d4 = 0;
#pragma unroll
  for (int k = 0; k < 16; ++k) d4 += (int)sH[r][k] * (int)sW4[j * 16 + k];
  signed char x5 = sgnf((float)d4 + b4[j]);
  __syncthreads();
  sH[r][j] = x5;
  __syncthreads();
  if (j < 10) {
    int d5 = 0;
#pragma unroll
    for (int k = 0; k < 16; ++k) d5 += (int)sH[r][k] * (int)sW5[j * 16 + k];
    A5[(size_t)(rowBlock + r) * 10 + j] = d5;
    atomicAdd(&bsum[j], d5);
    atomicAdd(&bsq[j], d5 * d5);
  }
  __syncthreads();
  if (t < 10) {
    atomicAdd(&sums5[t], (ull)(long long)bsum[t]);
    atomicAdd(&sums5[10 + t], (ull)(long long)bsq[t]);
  }
}

// ---------------- final BN + log_softmax ----------------
__global__ void k_lsm(const int* __restrict__ A5, const float* __restrict__ meanf,
                      const float* __restrict__ sgf, const float* __restrict__ be,
                      float* __restrict__ out, int M) {
  int r = blockIdx.x * blockDim.x + threadIdx.x;
  if (r >= M) return;
  float tv[10]; float mx = -3.0e38f;
#pragma unroll
  for (int j = 0; j < 10; ++j) {
    tv[j] = ((float)A5[(size_t)r * 10 + j] - meanf[j]) * sgf[j] + be[j];
    mx = fmaxf(mx, tv[j]);
  }
  float s = 0.f;
#pragma unroll
  for (int j = 0; j < 10; ++j) s += expf(tv[j] - mx);
  float lse = mx + logf(s);
#pragma unroll
  for (int j = 0; j < 10; ++j) out[(size_t)r * 10 + j] = tv[j] - lse;
}

extern "C" void kernel_launch(void* const* d_in, const int* in_sizes, int n_in,
                              void* d_out, int out_size, void* d_ws, size_t ws_size,
                              hipStream_t stream) {
  const float* x   = (const float*)d_in[0];
  const float* w0f = (const float*)d_in[1];
  const float* w1f = (const float*)d_in[3];
  const float* w2f = (const float*)d_in[5];
  const float* w3f = (const float*)d_in[7];  const float* b3f = (const float*)d_in[8];
  const float* w4f = (const float*)d_in[9];  const float* b4f = (const float*)d_in[10];
  const float* w5f = (const float*)d_in[11];
  const float* g0 = (const float*)d_in[13]; const float* be0 = (const float*)d_in[14];
  const float* g1 = (const float*)d_in[15]; const float* be1 = (const float*)d_in[16];
  const float* g2 = (const float*)d_in[17]; const float* be2 = (const float*)d_in[18];
  const float* g3 = (const float*)d_in[19]; const float* be3 = (const float*)d_in[20];

  const int M = in_sizes[0] / 3072;   // 16384
  char* w = (char*)d_ws;
  short* Abuf      = (short*)w;                          // 16384*4096*2 = 134217728
  signed char* X0  = (signed char*)(w + 134217728);      // 50331648
  signed char* Xb  = (signed char*)(w + 184549376);      // 67108864
  signed char* X3  = (signed char*)(w + 251658240);      // 4194304
  signed char* Ws0 = (signed char*)(w + 255852544);      // 12582912
  signed char* Ws1 = (signed char*)(w + 268435456);      // 16777216
  signed char* Ws2 = (signed char*)(w + 285212672);      // 1048576
  signed char* Ws3 = (signed char*)(w + 286261248);      // 4096
  signed char* Ws4 = (signed char*)(w + 286265344);      // 256
  signed char* Ws5 = (signed char*)(w + 286265600);      // 256 (160 used)
  int* A5          = (int*)(w + 286265856);              // 655360
  ull* S0          = (ull*)(w + 286921216);              // 65536
  ull* S1          = (ull*)(w + 286986752);              // 65536
  ull* S2          = (ull*)(w + 287052288);              // 4096
  ull* S5          = (ull*)(w + 287056384);              // 256 (160 used)
  float* P0m = (float*)(w + 287056640); float* P0s = (float*)(w + 287073024);
  float* P1m = (float*)(w + 287089408); float* P1s = (float*)(w + 287105792);
  float* P2m = (float*)(w + 287122176); float* P2s = (float*)(w + 287123200);
  float* P5m = (float*)(w + 287124224); float* P5s = (float*)(w + 287124288);

  // zero all stat accumulators (atomics accumulate fresh each call)
  hipMemsetAsync(w + 286921216, 0, 135424, stream);

  auto bin = [&](const float* src, signed char* dst, int n) {
    int n4 = n / 4;
    int grid = (n4 + 255) / 256; if (grid > 8192) grid = 8192;
    k_bin<<<grid, 256, 0, stream>>>((const float4*)src, (char4*)dst, n4);
  };
  bin(x,   X0,  M * 3072);
  bin(w0f, Ws0, 4096 * 3072);
  bin(w1f, Ws1, 4096 * 4096);
  bin(w2f, Ws2, 256 * 4096);
  bin(w3f, Ws3, 16 * 256);
  bin(w4f, Ws4, 16 * 16);
  bin(w5f, Ws5, 10 * 16);

  // Layer 0: [M,3072] x [4096,3072]^T
  k_bgemm<<<dim3(4096 / BN, M / BM), 256, 0, stream>>>(X0, Ws0, Abuf, M, 4096, 3072);
  k_colstats<<<dim3(4096 / 64, M / 1024), 256, 0, stream>>>(Abuf, M, 4096, 1024, S0);
  k_finalize<<<16, 256, 0, stream>>>(S0, g0, M, 4096, P0m, P0s);
  k_signbn<<<8192, 256, 0, stream>>>((const short4*)Abuf, P0m, P0s, be0, (char4*)Xb, M * 4096 / 4, 4095);

  // Layer 1: [M,4096] x [4096,4096]^T
  k_bgemm<<<dim3(4096 / BN, M / BM), 256, 0, stream>>>(Xb, Ws1, Abuf, M, 4096, 4096);
  k_colstats<<<dim3(4096 / 64, M / 1024), 256, 0, stream>>>(Abuf, M, 4096, 1024, S1);
  k_finalize<<<16, 256, 0, stream>>>(S1, g1, M, 4096, P1m, P1s);
  k_signbn<<<8192, 256, 0, stream>>>((const short4*)Abuf, P1m, P1s, be1, (char4*)Xb, M * 4096 / 4, 4095);

  // Layer 2: [M,4096] x [256,4096]^T
  k_bgemm<<<dim3(256 / BN, M / BM), 256, 0, stream>>>(Xb, Ws2, Abuf, M, 256, 4096);
  k_colstats<<<dim3(256 / 64, M / 1024), 256, 0, stream>>>(Abuf, M, 256, 1024, S2);
  k_finalize<<<1, 256, 0, stream>>>(S2, g2, M, 256, P2m, P2s);
  k_signbn<<<4096, 256, 0, stream>>>((const short4*)Abuf, P2m, P2s, be2, (char4*)X3, M * 256 / 4, 255);

  // Layers 3-5 fused + L5 stats
  k_tail<<<M / 16, 256, 0, stream>>>(X3, Ws3, Ws4, Ws5, b3f, b4f, A5, S5, M);
  k_finalize<<<1, 32, 0, stream>>>(S5, g3, M, 10, P5m, P5s);
  k_lsm<<<(M + 255) / 256, 256, 0, stream>>>(A5, P5m, P5s, be3, (float*)d_out, M);

  (void)n_in; (void)out_size; (void)ws_size;
}

// Round 2
// 713.822 us; speedup vs baseline: 4.0144x; 4.0144x over previous
//
#include <hip/hip_runtime.h>
#include <stdint.h>

typedef int v4i __attribute__((ext_vector_type(4)));
typedef unsigned long long ull;

#define GLOAD16(g, l)                                                          \
  __builtin_amdgcn_global_load_lds(                                            \
      (const __attribute__((address_space(1))) void*)(g),                      \
      (__attribute__((address_space(3))) void*)(l), 16, 0, 0)

__device__ __forceinline__ signed char sgnf(float v) {
  return v > 0.f ? (signed char)1 : (v < 0.f ? (signed char)-1 : (signed char)0);
}

// ---------------- binarize fp32 -> i8 sign ----------------
__global__ void k_bin(const float4* __restrict__ in, char4* __restrict__ out, int n4) {
  int i = blockIdx.x * blockDim.x + threadIdx.x;
  int stride = gridDim.x * blockDim.x;
  for (; i < n4; i += stride) {
    float4 v = in[i];
    char4 o;
    o.x = sgnf(v.x); o.y = sgnf(v.y); o.z = sgnf(v.z); o.w = sgnf(v.w);
    out[i] = o;
  }
}

// ---------------- i8 binary GEMM: A[M,N] = X[M,K] * W[N,K]^T, + fused col stats ----
// global_load_lds staging: linear LDS dest, inverse-swizzled global source,
// swizzled ds_read (rule #21). 2-barrier m97 structure.
#define BM 128
#define BN 128
#define BKB 128

__global__ __launch_bounds__(256, 2) void k_bgemm(
    const signed char* __restrict__ X, const signed char* __restrict__ W,
    short* __restrict__ A, ull* __restrict__ S, int M, int N, int K)
{
  __shared__ __align__(16) signed char As[BM * BKB];
  __shared__ __align__(16) signed char Bs[BN * BKB];
  const int t = threadIdx.x;
  const int lane = t & 63;
  const int wave = t >> 6;
  const int wm = wave >> 1, wn = wave & 1;
  const int bm = blockIdx.y * BM, bn = blockIdx.x * BN;

  // per-lane source-swizzle geometry for staging (8 rows x 128B per wave-issue)
  const int srow = lane >> 3;            // 0..7 row within chunk
  const int sslot = (lane & 7);          // linear 16B slot within row

  v4i acc[4][4] = {};

  for (int k0 = 0; k0 < K; k0 += BKB) {
#pragma unroll
    for (int c = 0; c < 4; ++c) {
      int br = (wave * 4 + c) * 8;                 // base row of this 8-row chunk
      int row = br + srow;
      int ss = sslot ^ (row & 7);                  // inverse swizzle on SOURCE
      GLOAD16(X + (size_t)(bm + row) * K + k0 + ss * 16, As + br * BKB);
      GLOAD16(W + (size_t)(bn + row) * K + k0 + ss * 16, Bs + br * BKB);
    }
    __syncthreads();   // drains vmcnt (loads -> LDS) + barrier
#pragma unroll
    for (int kk = 0; kk < 2; ++kk) {
      v4i af[4], bf[4];
#pragma unroll
      for (int m = 0; m < 4; ++m) {
        int row = wm * 64 + m * 16 + (lane & 15);
        int slot = ((kk << 2) | (lane >> 4)) ^ (row & 7);   // swizzle on READ
        af[m] = *(const v4i*)(As + row * BKB + slot * 16);
      }
#pragma unroll
      for (int n = 0; n < 4; ++n) {
        int row = wn * 64 + n * 16 + (lane & 15);
        int slot = ((kk << 2) | (lane >> 4)) ^ (row & 7);
        bf[n] = *(const v4i*)(Bs + row * BKB + slot * 16);
      }
#pragma unroll
      for (int m = 0; m < 4; ++m)
#pragma unroll
        for (int n = 0; n < 4; ++n)
          acc[m][n] = __builtin_amdgcn_mfma_i32_16x16x64_i8(af[m], bf[n], acc[m][n], 0, 0, 0);
    }
    __syncthreads();   // compute done before next tile overwrites LDS
  }

  // C layout (verified): col = lane&15, row = (lane>>4)*4 + reg
#pragma unroll
  for (int m = 0; m < 4; ++m) {
    int rbase = bm + wm * 64 + m * 16 + (lane >> 4) * 4;
#pragma unroll
    for (int n = 0; n < 4; ++n) {
      int col = bn + wn * 64 + n * 16 + (lane & 15);
#pragma unroll
      for (int r = 0; r < 4; ++r)
        A[(size_t)(rbase + r) * N + col] = (short)acc[m][n][r];
    }
  }

  // fused per-column stats: sum and sumsq of this block's 128 rows (int exact,
  // deterministic: integer atomics are associative)
#pragma unroll
  for (int n = 0; n < 4; ++n) {
    int s = 0, q = 0;
#pragma unroll
    for (int m = 0; m < 4; ++m)
#pragma unroll
      for (int r = 0; r < 4; ++r) {
        int v = acc[m][n][r];
        s += v; q += v * v;
      }
    s += __shfl_xor(s, 16); s += __shfl_xor(s, 32);
    q += __shfl_xor(q, 16); q += __shfl_xor(q, 32);
    if ((lane >> 4) == 0) {
      int col = bn + wn * 64 + n * 16 + (lane & 15);
      atomicAdd(&S[col], (ull)(long long)s);
      atomicAdd(&S[(size_t)N + col], (ull)(long long)q);
    }
  }
}

// ---------------- stats -> (mean, g*rsqrt(var+eps)) per column ----------------
__global__ void k_finalize(const ull* __restrict__ sums, const float* __restrict__ g,
                           int M, int N, float* __restrict__ meanf, float* __restrict__ sgf) {
  int j = blockIdx.x * blockDim.x + threadIdx.x;
  if (j >= N) return;
  double sum = (double)(long long)sums[j];
  double sumsq = (double)(long long)sums[N + j];
  double mean = sum / (double)M;
  double var = sumsq / (double)M - mean * mean;
  if (var < 0.0) var = 0.0;
  double inv = 1.0 / sqrt(var + 1e-5);
  meanf[j] = (float)mean;
  sgf[j] = (float)(inv * (double)g[j]);
}

// ---------------- sign(batchnorm(a)) -> i8 (bias cancels under BN) ----------------
__global__ void k_signbn(const short4* __restrict__ A4, const float* __restrict__ meanf,
                         const float* __restrict__ sgf, const float* __restrict__ be,
                         char4* __restrict__ X4, int total4, int nmask) {
  int i = blockIdx.x * blockDim.x + threadIdx.x;
  int stride = gridDim.x * blockDim.x;
  for (; i < total4; i += stride) {
    short4 a = A4[i];
    int c0 = (i * 4) & nmask;
    char4 o;
    o.x = sgnf(((float)a.x - meanf[c0    ]) * sgf[c0    ] + be[c0    ]);
    o.y = sgnf(((float)a.y - meanf[c0 + 1]) * sgf[c0 + 1] + be[c0 + 1]);
    o.z = sgnf(((float)a.z - meanf[c0 + 2]) * sgf[c0 + 2] + be[c0 + 2]);
    o.w = sgnf(((float)a.w - meanf[c0 + 3]) * sgf[c0 + 3] + be[c0 + 3]);
    X4[i] = o;
  }
}

// ---------------- fused layers 3,4,5: X3[M,256] -> A5[M,10] + stats ----------------
__global__ __launch_bounds__(256) void k_tail(
    const signed char* __restrict__ X3, const signed char* __restrict__ W3,
    const signed char* __restrict__ W4, const signed char* __restrict__ W5,
    const float* __restrict__ b3, const float* __restrict__ b4,
    int* __restrict__ A5, ull* __restrict__ sums5, int M)
{
  __shared__ __align__(16) signed char sW3[16 * 256];
  __shared__ __align__(16) signed char sW4[256];
  __shared__ __align__(16) signed char sW5[160];
  __shared__ __align__(16) signed char sX[16 * 256];
  __shared__ signed char sH[16][16];
  __shared__ int bsum[10], bsq[10];
  int t = threadIdx.x;
  int rowBlock = blockIdx.x * 16;
  ((int4*)sW3)[t] = ((const int4*)W3)[t];
  ((int4*)sX)[t] = ((const int4*)(X3 + (size_t)rowBlock * 256))[t];
  if (t < 16) ((int4*)sW4)[t] = ((const int4*)W4)[t];
  if (t < 10) {
    ((int4*)sW5)[t] = ((const int4*)W5)[t];
    bsum[t] = 0; bsq[t] = 0;
  }
  __syncthreads();
  int r = t >> 4, j = t & 15;
  int d3 = 0;
#pragma unroll 8
  for (int k = 0; k < 256; ++k) d3 += (int)sX[r * 256 + k] * (int)sW3[j * 256 + k];
  sH[r][j] = sgnf((float)d3 + b3[j]);   // sign(hardtanh(z)) == sign(z)
  __syncthreads();
  int d4 = 0;
#pragma unroll
  for (int k = 0; k < 16; ++k) d4 += (int)sH[r][k] * (int)sW4[j * 16 + k];
  signed char x5 = sgnf((float)d4 + b4[j]);
  __syncthreads();
  sH[r][j] = x5;
  __syncthreads();
  if (j < 10) {
    int d5 = 0;
#pragma unroll
    for (int k = 0; k < 16; ++k) d5 += (int)sH[r][k] * (int)sW5[j * 16 + k];
    A5[(size_t)(rowBlock + r) * 10 + j] = d5;
    atomicAdd(&bsum[j], d5);
    atomicAdd(&bsq[j], d5 * d5);
  }
  __syncthreads();
  if (t < 10) {
    atomicAdd(&sums5[t], (ull)(long long)bsum[t]);
    atomicAdd(&sums5[10 + t], (ull)(long long)bsq[t]);
  }
}

// ---------------- final BN + log_softmax ----------------
__global__ void k_lsm(const int* __restrict__ A5, const float* __restrict__ meanf,
                      const float* __restrict__ sgf, const float* __restrict__ be,
                      float* __restrict__ out, int M) {
  int r = blockIdx.x * blockDim.x + threadIdx.x;
  if (r >= M) return;
  float tv[10]; float mx = -3.0e38f;
#pragma unroll
  for (int j = 0; j < 10; ++j) {
    tv[j] = ((float)A5[(size_t)r * 10 + j] - meanf[j]) * sgf[j] + be[j];
    mx = fmaxf(mx, tv[j]);
  }
  float s = 0.f;
#pragma unroll
  for (int j = 0; j < 10; ++j) s += expf(tv[j] - mx);
  float lse = mx + logf(s);
#pragma unroll
  for (int j = 0; j < 10; ++j) out[(size_t)r * 10 + j] = tv[j] - lse;
}

extern "C" void kernel_launch(void* const* d_in, const int* in_sizes, int n_in,
                              void* d_out, int out_size, void* d_ws, size_t ws_size,
                              hipStream_t stream) {
  const float* x   = (const float*)d_in[0];
  const float* w0f = (const float*)d_in[1];
  const float* w1f = (const float*)d_in[3];
  const float* w2f = (const float*)d_in[5];
  const float* w3f = (const float*)d_in[7];  const float* b3f = (const float*)d_in[8];
  const float* w4f = (const float*)d_in[9];  const float* b4f = (const float*)d_in[10];
  const float* w5f = (const float*)d_in[11];
  const float* g0 = (const float*)d_in[13]; const float* be0 = (const float*)d_in[14];
  const float* g1 = (const float*)d_in[15]; const float* be1 = (const float*)d_in[16];
  const float* g2 = (const float*)d_in[17]; const float* be2 = (const float*)d_in[18];
  const float* g3 = (const float*)d_in[19]; const float* be3 = (const float*)d_in[20];

  const int M = in_sizes[0] / 3072;   // 16384
  char* w = (char*)d_ws;
  short* Abuf      = (short*)w;                          // 134217728
  signed char* X0  = (signed char*)(w + 134217728);      // 50331648
  signed char* Xb  = (signed char*)(w + 184549376);      // 67108864
  signed char* X3  = (signed char*)(w + 251658240);      // 4194304
  signed char* Ws0 = (signed char*)(w + 255852544);      // 12582912
  signed char* Ws1 = (signed char*)(w + 268435456);      // 16777216
  signed char* Ws2 = (signed char*)(w + 285212672);      // 1048576
  signed char* Ws3 = (signed char*)(w + 286261248);      // 4096
  signed char* Ws4 = (signed char*)(w + 286265344);      // 256
  signed char* Ws5 = (signed char*)(w + 286265600);      // 256 (160 used)
  int* A5          = (int*)(w + 286265856);              // 655360
  ull* S0          = (ull*)(w + 286921216);              // 65536
  ull* S1          = (ull*)(w + 286986752);              // 65536
  ull* S2          = (ull*)(w + 287052288);              // 4096
  ull* S5          = (ull*)(w + 287056384);              // 256 (160 used)
  float* P0m = (float*)(w + 287056640); float* P0s = (float*)(w + 287073024);
  float* P1m = (float*)(w + 287089408); float* P1s = (float*)(w + 287105792);
  float* P2m = (float*)(w + 287122176); float* P2s = (float*)(w + 287123200);
  float* P5m = (float*)(w + 287124224); float* P5s = (float*)(w + 287124288);

  // zero all stat accumulators (atomics accumulate fresh each call)
  hipMemsetAsync(w + 286921216, 0, 135424, stream);

  auto bin = [&](const float* src, signed char* dst, int n) {
    int n4 = n / 4;
    int grid = (n4 + 255) / 256; if (grid > 8192) grid = 8192;
    k_bin<<<grid, 256, 0, stream>>>((const float4*)src, (char4*)dst, n4);
  };
  bin(x,   X0,  M * 3072);
  bin(w0f, Ws0, 4096 * 3072);
  bin(w1f, Ws1, 4096 * 4096);
  bin(w2f, Ws2, 256 * 4096);
  bin(w3f, Ws3, 16 * 256);
  bin(w4f, Ws4, 16 * 16);
  bin(w5f, Ws5, 10 * 16);

  // Layer 0: [M,3072] x [4096,3072]^T  (stats fused into GEMM epilogue)
  k_bgemm<<<dim3(4096 / BN, M / BM), 256, 0, stream>>>(X0, Ws0, Abuf, S0, M, 4096, 3072);
  k_finalize<<<16, 256, 0, stream>>>(S0, g0, M, 4096, P0m, P0s);
  k_signbn<<<8192, 256, 0, stream>>>((const short4*)Abuf, P0m, P0s, be0, (char4*)Xb, M * 4096 / 4, 4095);

  // Layer 1: [M,4096] x [4096,4096]^T
  k_bgemm<<<dim3(4096 / BN, M / BM), 256, 0, stream>>>(Xb, Ws1, Abuf, S1, M, 4096, 4096);
  k_finalize<<<16, 256, 0, stream>>>(S1, g1, M, 4096, P1m, P1s);
  k_signbn<<<8192, 256, 0, stream>>>((const short4*)Abuf, P1m, P1s, be1, (char4*)Xb, M * 4096 / 4, 4095);

  // Layer 2: [M,4096] x [256,4096]^T
  k_bgemm<<<dim3(256 / BN, M / BM), 256, 0, stream>>>(Xb, Ws2, Abuf, S2, M, 256, 4096);
  k_finalize<<<1, 256, 0, stream>>>(S2, g2, M, 256, P2m, P2s);
  k_signbn<<<4096, 256, 0, stream>>>((const short4*)Abuf, P2m, P2s, be2, (char4*)X3, M * 256 / 4, 255);

  // Layers 3-5 fused + L5 stats
  k_tail<<<M / 16, 256, 0, stream>>>(X3, Ws3, Ws4, Ws5, b3f, b4f, A5, S5, M);
  k_finalize<<<1, 32, 0, stream>>>(S5, g3, M, 10, P5m, P5s);
  k_lsm<<<(M + 255) / 256, 256, 0, stream>>>(A5, P5m, P5s, be3, (float*)d_out, M);

  (void)n_in; (void)out_size; (void)ws_size;
}